// Round 3
// baseline (230.849 us; speedup 1.0000x reference)
//
#include <hip/hip_runtime.h>
#include <math.h>

#define CC 256   // columns
#define NN 512   // neurons per column
#define DD 256   // input dim (= D_CTX)
#define BB 64    // batch
#define KK 24    // top-k
#define WCAP 48  // winner-list capacity per row (>=24, slack for fp ties)

// ===========================================================================
// Kernel 0: xT[512][64]: d<256 -> x_in^T, d>=256 -> 0.3*x_ctx^T
// ===========================================================================
__global__ void transpose_x_kernel(const float* __restrict__ x_in,
                                   const float* __restrict__ x_ctx,
                                   float* __restrict__ xT) {
  int idx = blockIdx.x * blockDim.x + threadIdx.x;
  int d = idx >> 6;
  int b = idx & 63;
  float v = (d < DD) ? x_in[b * DD + d] : 0.3f * x_ctx[b * DD + (d - DD)];
  xT[idx] = v;
}

// ===========================================================================
// Kernel 1: boosted drive GEMM -> ws  [C][B][N]
// grid = 2*CC (column x n-half), block = 512, per-thread 2n x 16b
// ===========================================================================
__launch_bounds__(512)
__global__ void drive_gemm(const float* __restrict__ xT,      // [2D][B]
                           const float* __restrict__ W_ff,    // [C][D][N]
                           const float* __restrict__ W_ctx,   // [C][D][N]
                           const float* __restrict__ bias,    // [C][N]
                           const float* __restrict__ avg_act, // [C][N]
                           float* __restrict__ driveB) {      // [C][B][N]
  const int c = blockIdx.x >> 1;
  const int nh = blockIdx.x & 1;
  const int t = threadIdx.x;
  const int ng = t & 127;                         // 128 n-threads
  const int n0 = nh * 256 + ng * 2;
  const int b0 = __builtin_amdgcn_readfirstlane((t >> 7) * 16);

  float2 acc[16];
#pragma unroll
  for (int i = 0; i < 16; ++i) { acc[i].x = 0.f; acc[i].y = 0.f; }

  const float* __restrict__ wf = W_ff + (size_t)c * DD * NN + n0;
  const float* __restrict__ wc = W_ctx + (size_t)c * DD * NN + n0;

#pragma unroll 4
  for (int d = 0; d < DD; ++d) {
    const float2 w = *reinterpret_cast<const float2*>(wf + (size_t)d * NN);
    const float* __restrict__ xp = xT + d * BB + b0;  // uniform -> s_load
#pragma unroll
    for (int i = 0; i < 16; ++i) {
      const float xv = xp[i];
      acc[i].x = fmaf(xv, w.x, acc[i].x);
      acc[i].y = fmaf(xv, w.y, acc[i].y);
    }
  }
#pragma unroll 4
  for (int d = 0; d < DD; ++d) {
    const float2 w = *reinterpret_cast<const float2*>(wc + (size_t)d * NN);
    const float* __restrict__ xp = xT + (DD + d) * BB + b0;
#pragma unroll
    for (int i = 0; i < 16; ++i) {
      const float xv = xp[i];
      acc[i].x = fmaf(xv, w.x, acc[i].x);
      acc[i].y = fmaf(xv, w.y, acc[i].y);
    }
  }

  const float2 bz = *reinterpret_cast<const float2*>(bias + (size_t)c * NN + n0);
  const float2 av = *reinterpret_cast<const float2*>(avg_act + (size_t)c * NN + n0);
  float2 bo;
  bo.x = log1pf(0.05f / (av.x + 1e-6f));
  bo.y = log1pf(0.05f / (av.y + 1e-6f));

#pragma unroll
  for (int i = 0; i < 16; ++i) {
    float2 m2;
    m2.x = (acc[i].x + bz.x) + bo.x;
    m2.y = (acc[i].y + bz.y) + bo.y;
    *reinterpret_cast<float2*>(driveB + ((size_t)c * BB + (b0 + i)) * NN + n0) = m2;
  }
}

// ===========================================================================
// Kernel 2: top-k + normalize + activations + sparse predictions + errors
// grid = CC, block = 1024 (16 waves, 4 batch-rows each)
// ===========================================================================
__launch_bounds__(1024)
__global__ void sparse_pred(const float* __restrict__ x_in,    // [B][D]
                            const float* __restrict__ driveB,  // [C][B][N]
                            const float* __restrict__ W_pred,  // [C][N][D]
                            const float* __restrict__ avg_act, // [C][N]
                            float* __restrict__ out_act,       // [B][C][N]
                            float* __restrict__ out_pred,      // [B][C][D]
                            float* __restrict__ out_err) {     // [B][C][D]
  __shared__ int wcnt[BB];
  __shared__ float wlist[BB * WCAP * 2];  // {val, idx-bits}

  const int c = blockIdx.x;
  const int t = threadIdx.x;
  const int lane = t & 63;
  const int wv = t >> 6;  // 0..15

  // homeostatic boost for this lane's 8 n positions (same formula as kernel 1)
  float bo[8];
#pragma unroll
  for (int j = 0; j < 8; ++j)
    bo[j] = log1pf(0.05f / (avg_act[(size_t)c * NN + lane + 64 * j] + 1e-6f));

  // -------- per-wave rows: topk -> raw -> normalize -> act + winners -------
  for (int r = wv * 4; r < wv * 4 + 4; ++r) {
    const float* __restrict__ row = driveB + ((size_t)c * BB + r) * NN;
    float o[8], v[8];
#pragma unroll
    for (int j = 0; j < 8; ++j) { o[j] = row[lane + 64 * j]; v[j] = o[j]; }

    float kth = 0.f;
    for (int it = 0; it < KK; ++it) {
      float m = v[0];
#pragma unroll
      for (int j = 1; j < 8; ++j) m = fmaxf(m, v[j]);
#pragma unroll
      for (int off = 1; off <= 32; off <<= 1) m = fmaxf(m, __shfl_xor(m, off));
      kth = m;
      bool mine = false;
#pragma unroll
      for (int j = 0; j < 8; ++j) mine = mine || (v[j] == m);
      unsigned long long msk = __ballot(mine);
      int first = __ffsll(msk) - 1;
      if (lane == first) {
        bool done = false;
#pragma unroll
        for (int j = 0; j < 8; ++j) {
          bool cnd = (!done) && (v[j] == m);
          if (cnd) v[j] = -INFINITY;
          done = done || cnd;
        }
      }
    }

    float raw[8];
    float s = 0.f;
#pragma unroll
    for (int j = 0; j < 8; ++j) {
      const float rw = (o[j] >= kth) ? fmaxf(o[j] - bo[j], 0.f) : 0.f;
      raw[j] = rw;
      s += rw;
    }
#pragma unroll
    for (int off = 1; off <= 32; off <<= 1) s += __shfl_xor(s, off);
    const float sc = (float)KK / (s + 1e-8f);

    int base = 0;
#pragma unroll
    for (int j = 0; j < 8; ++j) {
      const int n = lane + 64 * j;
      const float a = raw[j] * sc;
      out_act[(size_t)r * (CC * NN) + (size_t)c * NN + n] = a;
      const bool win = a > 0.f;
      unsigned long long m = __ballot(win);
      int pos = base + __popcll(m & ((1ull << lane) - 1ull));
      if (win && pos < WCAP) {
        const int slot = (r * WCAP + pos) * 2;
        wlist[slot] = a;
        reinterpret_cast<int*>(wlist)[slot + 1] = n;
      }
      base += (int)__popcll(m);
    }
    if (lane == 0) wcnt[r] = (base < WCAP) ? base : WCAP;
  }
  __syncthreads();

  // -------------------- sparse predictions + errors ------------------------
  {
    const int dq = t & 63;
    const int d0 = dq * 4;
    const int grp = t >> 6;  // 0..15 -> 4 batches each
    const float* __restrict__ wp = W_pred + (size_t)c * NN * DD;
    for (int bi = 0; bi < 4; ++bi) {
      const int b = grp * 4 + bi;
      const int cnt = wcnt[b];
      float4 p = make_float4(0.f, 0.f, 0.f, 0.f);
      float4 q = make_float4(0.f, 0.f, 0.f, 0.f);
      int i = 0;
      for (; i + 2 <= cnt; i += 2) {
        const int s0 = (b * WCAP + i) * 2;
        const int s1 = s0 + 2;
        const float a0 = wlist[s0];
        const int nn0 = reinterpret_cast<const int*>(wlist)[s0 + 1];
        const float a1 = wlist[s1];
        const int nn1 = reinterpret_cast<const int*>(wlist)[s1 + 1];
        const float4 w0 = *reinterpret_cast<const float4*>(wp + (size_t)nn0 * DD + d0);
        const float4 w1 = *reinterpret_cast<const float4*>(wp + (size_t)nn1 * DD + d0);
        p.x = fmaf(a0, w0.x, p.x); p.y = fmaf(a0, w0.y, p.y);
        p.z = fmaf(a0, w0.z, p.z); p.w = fmaf(a0, w0.w, p.w);
        q.x = fmaf(a1, w1.x, q.x); q.y = fmaf(a1, w1.y, q.y);
        q.z = fmaf(a1, w1.z, q.z); q.w = fmaf(a1, w1.w, q.w);
      }
      if (i < cnt) {
        const int s0 = (b * WCAP + i) * 2;
        const float a0 = wlist[s0];
        const int nn0 = reinterpret_cast<const int*>(wlist)[s0 + 1];
        const float4 w0 = *reinterpret_cast<const float4*>(wp + (size_t)nn0 * DD + d0);
        p.x = fmaf(a0, w0.x, p.x); p.y = fmaf(a0, w0.y, p.y);
        p.z = fmaf(a0, w0.z, p.z); p.w = fmaf(a0, w0.w, p.w);
      }
      float4 r4;
      r4.x = p.x + q.x; r4.y = p.y + q.y; r4.z = p.z + q.z; r4.w = p.w + q.w;
      const float4 xi = *reinterpret_cast<const float4*>(x_in + (size_t)b * DD + d0);
      float4 e4;
      e4.x = xi.x - r4.x; e4.y = xi.y - r4.y; e4.z = xi.z - r4.z; e4.w = xi.w - r4.w;
      *reinterpret_cast<float4*>(out_pred + (size_t)b * (CC * DD) + (size_t)c * DD + d0) = r4;
      *reinterpret_cast<float4*>(out_err + (size_t)b * (CC * DD) + (size_t)c * DD + d0) = e4;
    }
  }
}

// ===========================================================================
// Fallback fused kernel (R2, proven at 219 us) for small ws_size
// ===========================================================================
#define MAT_F (BB * NN)
#define FSMEM_FLOATS (MAT_F + BB + BB + NN + BB + BB * WCAP * 2)
#define FSMEM_BYTES (FSMEM_FLOATS * 4)

__launch_bounds__(1024)
__global__ void cortical_fused(const float* __restrict__ x_in,
                               const float* __restrict__ xT,
                               const float* __restrict__ W_ff,
                               const float* __restrict__ W_ctx,
                               const float* __restrict__ W_pred,
                               const float* __restrict__ bias,
                               const float* __restrict__ avg_act,
                               float* __restrict__ out_act,
                               float* __restrict__ out_pred,
                               float* __restrict__ out_err) {
  extern __shared__ float smem[];
  float* mat = smem;
  float* thr = smem + MAT_F;
  float* scl = thr + BB;
  float* boostS = scl + BB;
  int* wcnt = (int*)(boostS + NN);
  float* wlist = (float*)(wcnt + BB);

  const int c = blockIdx.x;
  const int t = threadIdx.x;
  const int lane = t & 63;
  const int wv = t >> 6;

  if (t < NN) boostS[t] = log1pf(0.05f / (avg_act[c * NN + t] + 1e-6f));
  __syncthreads();

  const int ng = t & 255;
  const int n0 = ng * 2;
  const int b0 = __builtin_amdgcn_readfirstlane((t >> 8) * 16);

  float acc[16][2];
#pragma unroll
  for (int i = 0; i < 16; ++i) { acc[i][0] = 0.f; acc[i][1] = 0.f; }

  const float* __restrict__ wf = W_ff + (size_t)c * DD * NN + n0;
  const float* __restrict__ wc = W_ctx + (size_t)c * DD * NN + n0;

#pragma unroll 4
  for (int d = 0; d < DD; ++d) {
    const float2 w = *reinterpret_cast<const float2*>(wf + (size_t)d * NN);
    const float* __restrict__ xp = xT + d * BB + b0;
#pragma unroll
    for (int i = 0; i < 16; ++i) {
      const float xv = xp[i];
      acc[i][0] = fmaf(xv, w.x, acc[i][0]);
      acc[i][1] = fmaf(xv, w.y, acc[i][1]);
    }
  }
#pragma unroll 4
  for (int d = 0; d < DD; ++d) {
    const float2 w = *reinterpret_cast<const float2*>(wc + (size_t)d * NN);
    const float* __restrict__ xp = xT + (DD + d) * BB + b0;
#pragma unroll
    for (int i = 0; i < 16; ++i) {
      const float xv = xp[i];
      acc[i][0] = fmaf(xv, w.x, acc[i][0]);
      acc[i][1] = fmaf(xv, w.y, acc[i][1]);
    }
  }

  const float2 bz = *reinterpret_cast<const float2*>(bias + (size_t)c * NN + n0);
  const float2 bo = *reinterpret_cast<const float2*>(boostS + n0);
#pragma unroll
  for (int i = 0; i < 16; ++i) {
    float2 m2;
    m2.x = (acc[i][0] + bz.x) + bo.x;
    m2.y = (acc[i][1] + bz.y) + bo.y;
    *reinterpret_cast<float2*>(mat + (size_t)(b0 + i) * NN + n0) = m2;
  }
  __syncthreads();

  for (int r = wv * 4; r < wv * 4 + 4; ++r) {
    float v[8];
#pragma unroll
    for (int j = 0; j < 8; ++j) v[j] = mat[r * NN + lane + 64 * j];
    float kth = 0.f;
    for (int it = 0; it < KK; ++it) {
      float m = v[0];
#pragma unroll
      for (int j = 1; j < 8; ++j) m = fmaxf(m, v[j]);
#pragma unroll
      for (int off = 1; off <= 32; off <<= 1) m = fmaxf(m, __shfl_xor(m, off));
      kth = m;
      bool mine = false;
#pragma unroll
      for (int j = 0; j < 8; ++j) mine = mine || (v[j] == m);
      unsigned long long msk = __ballot(mine);
      int first = __ffsll(msk) - 1;
      if (lane == first) {
        bool done = false;
#pragma unroll
        for (int j = 0; j < 8; ++j) {
          bool cnd = (!done) && (v[j] == m);
          if (cnd) v[j] = -INFINITY;
          done = done || cnd;
        }
      }
    }
    if (lane == 0) thr[r] = kth;
  }
  __syncthreads();

  for (int r = wv * 4; r < wv * 4 + 4; ++r) {
    const float tb = thr[r];
    float raw[8];
    float s = 0.f;
#pragma unroll
    for (int j = 0; j < 8; ++j) {
      const int n = lane + 64 * j;
      const float bv = mat[r * NN + n];
      const float rw = (bv >= tb) ? fmaxf(bv - boostS[n], 0.f) : 0.f;
      raw[j] = rw;
      s += rw;
    }
#pragma unroll
    for (int off = 1; off <= 32; off <<= 1) s += __shfl_xor(s, off);
    const float sc = (float)KK / (s + 1e-8f);

    int base = 0;
#pragma unroll
    for (int j = 0; j < 8; ++j) {
      const int n = lane + 64 * j;
      const float a = raw[j] * sc;
      out_act[(size_t)r * (CC * NN) + (size_t)c * NN + n] = a;
      const bool win = a > 0.f;
      unsigned long long m = __ballot(win);
      int pos = base + __popcll(m & ((1ull << lane) - 1ull));
      if (win && pos < WCAP) {
        const int slot = (r * WCAP + pos) * 2;
        wlist[slot] = a;
        reinterpret_cast<int*>(wlist)[slot + 1] = n;
      }
      base += (int)__popcll(m);
    }
    if (lane == 0) wcnt[r] = (base < WCAP) ? base : WCAP;
  }
  __syncthreads();

  {
    const int dq = t & 63;
    const int d0 = dq * 4;
    const int grp = t >> 6;
    const float* __restrict__ wp = W_pred + (size_t)c * NN * DD;
    for (int bi = 0; bi < 4; ++bi) {
      const int b = grp * 4 + bi;
      const int cnt = wcnt[b];
      float4 p = make_float4(0.f, 0.f, 0.f, 0.f);
      float4 q = make_float4(0.f, 0.f, 0.f, 0.f);
      int i = 0;
      for (; i + 2 <= cnt; i += 2) {
        const int s0 = (b * WCAP + i) * 2;
        const int s1 = s0 + 2;
        const float a0 = wlist[s0];
        const int nn0 = reinterpret_cast<const int*>(wlist)[s0 + 1];
        const float a1 = wlist[s1];
        const int nn1 = reinterpret_cast<const int*>(wlist)[s1 + 1];
        const float4 w0 = *reinterpret_cast<const float4*>(wp + (size_t)nn0 * DD + d0);
        const float4 w1 = *reinterpret_cast<const float4*>(wp + (size_t)nn1 * DD + d0);
        p.x = fmaf(a0, w0.x, p.x); p.y = fmaf(a0, w0.y, p.y);
        p.z = fmaf(a0, w0.z, p.z); p.w = fmaf(a0, w0.w, p.w);
        q.x = fmaf(a1, w1.x, q.x); q.y = fmaf(a1, w1.y, q.y);
        q.z = fmaf(a1, w1.z, q.z); q.w = fmaf(a1, w1.w, q.w);
      }
      if (i < cnt) {
        const int s0 = (b * WCAP + i) * 2;
        const float a0 = wlist[s0];
        const int nn0 = reinterpret_cast<const int*>(wlist)[s0 + 1];
        const float4 w0 = *reinterpret_cast<const float4*>(wp + (size_t)nn0 * DD + d0);
        p.x = fmaf(a0, w0.x, p.x); p.y = fmaf(a0, w0.y, p.y);
        p.z = fmaf(a0, w0.z, p.z); p.w = fmaf(a0, w0.w, p.w);
      }
      float4 r4;
      r4.x = p.x + q.x; r4.y = p.y + q.y; r4.z = p.z + q.z; r4.w = p.w + q.w;
      const float4 xi = *reinterpret_cast<const float4*>(x_in + (size_t)b * DD + d0);
      float4 e4;
      e4.x = xi.x - r4.x; e4.y = xi.y - r4.y; e4.z = xi.z - r4.z; e4.w = xi.w - r4.w;
      *reinterpret_cast<float4*>(out_pred + (size_t)b * (CC * DD) + (size_t)c * DD + d0) = r4;
      *reinterpret_cast<float4*>(out_err + (size_t)b * (CC * DD) + (size_t)c * DD + d0) = e4;
    }
  }
}

extern "C" void kernel_launch(void* const* d_in, const int* in_sizes, int n_in,
                              void* d_out, int out_size, void* d_ws, size_t ws_size,
                              hipStream_t stream) {
  const float* x_in = (const float*)d_in[0];
  const float* x_ctx = (const float*)d_in[1];
  const float* W_ff = (const float*)d_in[2];
  const float* W_ctx = (const float*)d_in[3];
  const float* W_pred = (const float*)d_in[4];
  const float* bias = (const float*)d_in[5];
  const float* avg = (const float*)d_in[6];

  float* out = (float*)d_out;
  float* out_act = out;                              // [B][C][N]
  float* out_pred = out + (size_t)BB * CC * NN;      // [B][C][D]
  float* out_err = out_pred + (size_t)BB * CC * DD;  // [B][C][D]

  float* xT = (float*)d_ws;                          // [2*DD][BB]
  float* driveB = xT + 2 * BB * DD;                  // [C][B][N]

  const size_t need_bytes = (size_t)(2 * BB * DD + (size_t)CC * BB * NN) * 4;

  transpose_x_kernel<<<(2 * BB * DD) / 256, 256, 0, stream>>>(x_in, x_ctx, xT);

  if (ws_size >= need_bytes) {
    drive_gemm<<<2 * CC, 512, 0, stream>>>(xT, W_ff, W_ctx, bias, avg, driveB);
    sparse_pred<<<CC, 1024, 0, stream>>>(x_in, driveB, W_pred, avg, out_act,
                                         out_pred, out_err);
  } else {
    hipFuncSetAttribute((const void*)cortical_fused,
                        hipFuncAttributeMaxDynamicSharedMemorySize, FSMEM_BYTES);
    cortical_fused<<<CC, 1024, FSMEM_BYTES, stream>>>(x_in, xT, W_ff, W_ctx,
                                                      W_pred, bias, avg, out_act,
                                                      out_pred, out_err);
  }
}